// Round 15
// baseline (451.958 us; speedup 1.0000x reference)
//
#include <hip/hip_runtime.h>
#include <math.h>

#define NB 128            // graphs
#define NN 1024           // nodes per graph
#define BNODES (NB*NN)    // 131072
#define NE 2097152        // edges
#define EPG (NE/NB)       // 16384 edges per graph (edge list is graph-blocked)
#define EPT (EPG/NN)      // 16 edges per thread in k_csr
#define FH 64             // hidden
#define KK1 820
#define KK2 656
#define KK3 525

// ---------------- one-kernel CSR build + layer-1 degrees ----------------
__global__ __launch_bounds__(1024) void k_csr(const int* __restrict__ ei,
                                              const float* __restrict__ ea,
                                              int* __restrict__ rowptr,
                                              int2* __restrict__ csr_sw,
                                              int* __restrict__ aliveA,
                                              float* __restrict__ dinvW,
                                              float* __restrict__ dinvU) {
  extern __shared__ int2 lcsr[];          // EPG entries = 128 KB
  __shared__ int cnt[NN];
  __shared__ int cur[NN];
  __shared__ float wsum[NN];
  int b = blockIdx.x, t = threadIdx.x;
  int node = b*NN + t;
  aliveA[node] = 1;
  cnt[t] = 0;
  wsum[t] = 0.f;
  __syncthreads();
  int ebase = b*EPG;
  int se[EPT]; int de[EPT]; float we[EPT];
  #pragma unroll
  for (int i = 0; i < EPT; ++i) {
    int e = ebase + i*NN + t;
    se[i] = ei[e];
    de[i] = ei[NE + e] - b*NN;
    we[i] = ea[e];
    atomicAdd(&cnt[de[i]], 1);
    atomicAdd(&wsum[de[i]], we[i]);
  }
  __syncthreads();
  int v = cnt[t];
  for (int off = 1; off < NN; off <<= 1) {
    int u = (t >= off) ? cnt[t - off] : 0;
    __syncthreads();
    cnt[t] += u;
    __syncthreads();
  }
  int excl = cnt[t] - v;
  rowptr[node] = ebase + excl;
  cur[t] = excl;
  dinvW[node] = rsqrtf(1.f + wsum[t]);
  dinvU[node] = rsqrtf(1.f + (float)v);
  if (b == NB-1 && t == NN-1) rowptr[BNODES] = NE;
  __syncthreads();
  #pragma unroll
  for (int i = 0; i < EPT; ++i) {
    int pos = atomicAdd(&cur[de[i]], 1);
    lcsr[pos] = make_int2(se[i], __float_as_int(we[i]));
  }
  __syncthreads();
  float4* dst4 = (float4*)(csr_sw + ebase);
  const float4* src4 = (const float4*)lcsr;
  #pragma unroll
  for (int i = 0; i < EPG/2/NN; ++i)
    dst4[i*NN + t] = src4[i*NN + t];
}

// ---------------- degrees (layers 2,3): 16-lane group per node ----------------
template<int MODE>
__global__ void k_degs(const int* __restrict__ rowptr, const int2* __restrict__ csr_sw,
                       const int* __restrict__ alive,
                       float* __restrict__ dinvW, float* __restrict__ dinvU) {
  int t = threadIdx.x;
  int l16 = t & 15;
  int d = blockIdx.x*16 + (t >> 4);
  int r0 = rowptr[d], r1 = rowptr[d+1];
  float sW = 0.f, sU = 0.f;
  for (int base = r0; base < r1; base += 16) {
    if (base + l16 < r1) {
      int2 p = csr_sw[base + l16];
      if (alive[p.x]) { sW += (MODE == 2) ? 1.f : __int_as_float(p.y); sU += 1.f; }
    }
  }
  #pragma unroll
  for (int off = 8; off; off >>= 1) {
    sW += __shfl_xor(sW, off, 16);
    sU += __shfl_xor(sU, off, 16);
  }
  if (l16 == 0) {
    bool dA = (alive[d] != 0);
    dinvW[d] = dA ? rsqrtf(1.f + sW) : 0.f;
    dinvU[d] = dA ? rsqrtf(1.f + sU) : 0.f;
  }
}

// ---------------- layer-1 input transform (2 -> 64) ----------------
__global__ void k_lin1(const float* __restrict__ x, const float* __restrict__ W,
                       float* __restrict__ h) {
  int i = blockIdx.x*256 + threadIdx.x;
  if (i >= BNODES*FH) return;
  int node = i >> 6, f = i & 63;
  h[i] = x[2*node]*W[f] + x[2*node+1]*W[FH + f];
}

// ---------------- fused pool-scale + 64x64 linear ----------------
__global__ void k_lin64(const float* __restrict__ hA, const float* __restrict__ tm,
                        const float* __restrict__ W, float* __restrict__ hB) {
  __shared__ float sX[64][65];
  __shared__ float sW[64*64];
  int t = threadIdx.x;
  for (int i = t; i < 1024; i += 256) ((float4*)sW)[i] = ((const float4*)W)[i];
  int nb = blockIdx.x * 64;
  #pragma unroll
  for (int i = 0; i < 16; ++i) {
    int gidx = (nb << 6) + i*256 + t;
    int node = gidx >> 6, f = gidx & 63;
    sX[node - nb][f] = hA[gidx] * tm[node];
  }
  __syncthreads();
  int node = t >> 2;
  int f0 = (t & 3) * 16;
  float4 a0 = {0,0,0,0}, a1 = a0, a2 = a0, a3 = a0;
  #pragma unroll 4
  for (int k = 0; k < 64; ++k) {
    float xv = sX[node][k];
    const float4 w0 = *(const float4*)&sW[k*64 + f0];
    const float4 w1 = *(const float4*)&sW[k*64 + f0 + 4];
    const float4 w2 = *(const float4*)&sW[k*64 + f0 + 8];
    const float4 w3 = *(const float4*)&sW[k*64 + f0 + 12];
    a0.x = fmaf(xv, w0.x, a0.x); a0.y = fmaf(xv, w0.y, a0.y);
    a0.z = fmaf(xv, w0.z, a0.z); a0.w = fmaf(xv, w0.w, a0.w);
    a1.x = fmaf(xv, w1.x, a1.x); a1.y = fmaf(xv, w1.y, a1.y);
    a1.z = fmaf(xv, w1.z, a1.z); a1.w = fmaf(xv, w1.w, a1.w);
    a2.x = fmaf(xv, w2.x, a2.x); a2.y = fmaf(xv, w2.y, a2.y);
    a2.z = fmaf(xv, w2.z, a2.z); a2.w = fmaf(xv, w2.w, a2.w);
    a3.x = fmaf(xv, w3.x, a3.x); a3.y = fmaf(xv, w3.y, a3.y);
    a3.z = fmaf(xv, w3.z, a3.z); a3.w = fmaf(xv, w3.w, a3.w);
  }
  float4* dst = (float4*)(hB + (size_t)(nb + node)*FH + f0);
  dst[0] = a0; dst[1] = a1; dst[2] = a2; dst[3] = a3;
}

// ---------------- LDS-staged GCN gather: 1 block per (graph, feature-half) ----------------
// Stage hB[graph][*][half*32..+32) (128 KB) + dinvW (4 KB) in LDS; 8-lane
// group per dst node reads source rows from LDS instead of L2. Writes hA
// half-rows and the per-half scoring-dot partial qpart.
template<int MODE>
__global__ __launch_bounds__(1024) void k_gath(
    const int* __restrict__ rowptr, const int2* __restrict__ csr_sw,
    const float* __restrict__ dinvW, const float* __restrict__ hB,
    const float* __restrict__ bias, const float* __restrict__ Wp,
    float* __restrict__ hA, float* __restrict__ qpart) {
  extern __shared__ float sHB[];        // [NN][32] = 128 KB
  __shared__ float sDW[NN];
  __shared__ float sWp[32];
  __shared__ float sB[32];
  int b = blockIdx.x >> 1, half = blockIdx.x & 1;
  int t = threadIdx.x, l8 = t & 7;
  int gbase = b*NN;
  sDW[t] = dinvW[gbase + t];
  if (t < 32) { sWp[t] = Wp[half*32 + t]; sB[t] = bias[half*32 + t]; }
  const float4* hB4 = (const float4*)hB;
  float4* sHB4 = (float4*)sHB;
  #pragma unroll
  for (int i = 0; i < 8; ++i) {
    int idx = i*1024 + t;               // 8192 float4 = 1024 rows x 8
    int n = idx >> 3, j = idx & 7;
    sHB4[n*8 + j] = hB4[(size_t)(gbase + n)*16 + half*8 + j];
  }
  __syncthreads();
  float4 bv = ((const float4*)sB)[l8];
  float4 wp = ((const float4*)sWp)[l8];
  #pragma unroll 1
  for (int pass = 0; pass < 8; ++pass) {
    int n = pass*128 + (t >> 3);
    int gn = gbase + n;
    float dd = sDW[n];
    float4 hv = sHB4[n*8 + l8];
    float dd2 = dd*dd;
    float4 acc;
    acc.x = fmaf(dd2, hv.x, bv.x);
    acc.y = fmaf(dd2, hv.y, bv.y);
    acc.z = fmaf(dd2, hv.z, bv.z);
    acc.w = fmaf(dd2, hv.w, bv.w);
    int r0 = rowptr[gn], r1 = rowptr[gn+1];
    for (int base = r0; base < r1; base += 8) {
      int sj = 0; float cj = 0.f;
      if (base + l8 < r1) {
        int2 p = csr_sw[base + l8];
        sj = p.x - gbase;
        float w = (MODE == 2) ? 1.f : __int_as_float(p.y);
        cj = sDW[sj] * w * dd;          // 0 if src or dst dead
      }
      #pragma unroll
      for (int j = 0; j < 8; ++j) {
        int s   = __shfl(sj, j, 8);
        float c = __shfl(cj, j, 8);
        float4 v = sHB4[s*8 + l8];
        acc.x = fmaf(c, v.x, acc.x);
        acc.y = fmaf(c, v.y, acc.y);
        acc.z = fmaf(c, v.z, acc.z);
        acc.w = fmaf(c, v.w, acc.w);
      }
    }
    acc.x = fmaxf(acc.x, 0.f); acc.y = fmaxf(acc.y, 0.f);
    acc.z = fmaxf(acc.z, 0.f); acc.w = fmaxf(acc.w, 0.f);
    ((float4*)hA)[(size_t)gn*16 + half*8 + l8] = acc;
    float dot = acc.x*wp.x + acc.y*wp.y + acc.z*wp.z + acc.w*wp.w;
    dot += __shfl_xor(dot, 4, 8);
    dot += __shfl_xor(dot, 2, 8);
    dot += __shfl_xor(dot, 1, 8);
    if (l8 == 0) qpart[half*BNODES + gn] = dot;
  }
}

// ---------------- q finalize: q = dinvU * (qp0 + qp1) ----------------
__global__ void k_qfin(const float* __restrict__ dinvU, const float* __restrict__ qp,
                       float* __restrict__ q) {
  int i = blockIdx.x*256 + threadIdx.x;
  if (i < BNODES) q[i] = dinvU[i]*(qp[i] + qp[BNODES + i]);
}

// ---------------- scoring aggregation (q is self-masking) ----------------
__global__ void k_score(const int* __restrict__ rowptr, const int2* __restrict__ csr_sw,
                        const float* __restrict__ dinvU, const float* __restrict__ q,
                        const float* __restrict__ bp, float* __restrict__ score) {
  int t = threadIdx.x;
  int l16 = t & 15;
  int d = blockIdx.x*16 + (t >> 4);
  float du = dinvU[d];
  float sum = 0.f;
  if (du != 0.f) {
    int r0 = rowptr[d], r1 = rowptr[d+1];
    for (int base = r0; base < r1; base += 16)
      if (base + l16 < r1) sum += q[csr_sw[base + l16].x];
  }
  #pragma unroll
  for (int off = 8; off; off >>= 1) sum += __shfl_xor(sum, off, 16);
  if (l16 == 0) score[d] = bp[0] + du*(q[d] + sum);
}

// ---------------- top-k rank: 4 blocks/graph, 256 threads, thread = node ----------------
__global__ void k_topk(const float* __restrict__ score,
                       const int* __restrict__ alive, int k,
                       float* __restrict__ tm, int* __restrict__ aliveNext) {
  __shared__ float sc[NN];
  int b = blockIdx.x >> 2, p = blockIdx.x & 3;
  int t = threadIdx.x;
  int gbase = b*NN;
  #pragma unroll
  for (int i = 0; i < 4; ++i) {
    int n = i*256 + t;
    sc[n] = alive[gbase + n] ? score[gbase + n] : -INFINITY;
  }
  __syncthreads();
  int n = p*256 + t;              // this thread's node
  int node = gbase + n;
  float me = sc[n];
  float raw = score[node];
  int rank = 0;
  const float4* sc4 = (const float4*)sc;
  for (int j4 = 0; j4 < NN/4; ++j4) {
    float4 o = sc4[j4];
    int jb = j4*4;
    rank += (o.x > me) || (o.x == me && jb+0 < n);
    rank += (o.y > me) || (o.y == me && jb+1 < n);
    rank += (o.z > me) || (o.z == me && jb+2 < n);
    rank += (o.w > me) || (o.w == me && jb+3 < n);
  }
  int sel = (rank < k) ? 1 : 0;
  aliveNext[node] = sel;
  tm[node] = sel ? tanhf(raw) : 0.f;
}

// ---------------- pool-scale (virtual) + partial readout ----------------
__global__ void k_sread(const float* __restrict__ hA, const float* __restrict__ tm,
                        const int* __restrict__ aliveN,
                        float* __restrict__ pmax, float* __restrict__ psum) {
  __shared__ float rm[4][FH], rs[4][FH];
  int b = blockIdx.x >> 2, p = blockIdx.x & 3;
  int t = threadIdx.x, f = t & 63, r = t >> 6;
  float mx = -INFINITY, sm = 0.f;
  for (int i = 0; i < 64; ++i) {
    int n = p*256 + i*4 + r;
    int node = b*NN + n;
    float v = hA[(size_t)node*FH + f] * tm[node];
    if (aliveN[node]) { mx = fmaxf(mx, v); sm += v; }
  }
  rm[r][f] = mx; rs[r][f] = sm;
  __syncthreads();
  if (t < FH) {
    float m2 = fmaxf(fmaxf(rm[0][t], rm[1][t]), fmaxf(rm[2][t], rm[3][t]));
    float s2 = rs[0][t] + rs[1][t] + rs[2][t] + rs[3][t];
    pmax[(b*4 + p)*FH + t] = m2;
    psum[(b*4 + p)*FH + t] = s2;
  }
}

// ---------------- partial reduce + MLP head + log_softmax ----------------
__global__ void k_mlp(const float* __restrict__ pmax, const float* __restrict__ psum,
                      const float* __restrict__ Wl1, const float* __restrict__ bl1,
                      const float* __restrict__ Wl2, const float* __restrict__ bl2,
                      const float* __restrict__ Wl3, const float* __restrict__ bl3,
                      float* __restrict__ out) {
  __shared__ float sg[2*FH];
  __shared__ float l1[FH];
  __shared__ float l2[FH/2];
  __shared__ float l3[2];
  int b = blockIdx.x, t = threadIdx.x;
  const float kf[3] = {(float)KK1, (float)KK2, (float)KK3};
  float gm = 0.f, gs = 0.f;
  #pragma unroll
  for (int l = 0; l < 3; ++l) {
    const float* pm = pmax + (size_t)l*NB*4*FH + (b*4)*FH;
    const float* ps = psum + (size_t)l*NB*4*FH + (b*4)*FH;
    float mm = -INFINITY, ss = 0.f;
    #pragma unroll
    for (int p = 0; p < 4; ++p) {
      mm = fmaxf(mm, pm[p*FH + t]);
      ss += ps[p*FH + t];
    }
    gm += mm;
    gs += ss / kf[l];
  }
  sg[t] = gm;
  sg[FH + t] = gs;
  __syncthreads();
  float acc = bl1[t];
  #pragma unroll
  for (int k = 0; k < 2*FH; ++k) acc = fmaf(sg[k], Wl1[k*FH + t], acc);
  l1[t] = fmaxf(acc, 0.f);
  __syncthreads();
  if (t < 32) {
    float a2 = bl2[t];
    #pragma unroll
    for (int k = 0; k < FH; ++k) a2 = fmaf(l1[k], Wl2[k*32 + t], a2);
    l2[t] = fmaxf(a2, 0.f);
  }
  __syncthreads();
  if (t < 2) {
    float a3 = bl3[t];
    #pragma unroll
    for (int k = 0; k < 32; ++k) a3 = fmaf(l2[k], Wl3[k*2 + t], a3);
    l3[t] = a3;
  }
  __syncthreads();
  if (t == 0) {
    float m = fmaxf(l3[0], l3[1]);
    float lse = m + logf(expf(l3[0]-m) + expf(l3[1]-m));
    out[b*2+0] = l3[0] - lse;
    out[b*2+1] = l3[1] - lse;
  }
}

extern "C" void kernel_launch(void* const* d_in, const int* in_sizes, int n_in,
                              void* d_out, int out_size, void* d_ws, size_t ws_size,
                              hipStream_t stream) {
  const float* x   = (const float*)d_in[0];
  const float* ea  = (const float*)d_in[1];
  const float* W1  = (const float*)d_in[2];
  const float* b1  = (const float*)d_in[3];
  const float* Wp1 = (const float*)d_in[4];
  const float* bp1 = (const float*)d_in[5];
  const float* W2  = (const float*)d_in[6];
  const float* b2  = (const float*)d_in[7];
  const float* Wp2 = (const float*)d_in[8];
  const float* bp2 = (const float*)d_in[9];
  const float* W3  = (const float*)d_in[10];
  const float* b3  = (const float*)d_in[11];
  const float* Wp3 = (const float*)d_in[12];
  const float* bp3 = (const float*)d_in[13];
  const float* Wl1 = (const float*)d_in[14];
  const float* bl1 = (const float*)d_in[15];
  const float* Wl2 = (const float*)d_in[16];
  const float* bl2 = (const float*)d_in[17];
  const float* Wl3 = (const float*)d_in[18];
  const float* bl3 = (const float*)d_in[19];
  const int*   ei  = (const int*)d_in[20];
  float* out = (float*)d_out;

  int2* csr_sw = (int2*)d_ws;                        // NE
  float* hA    = (float*)(csr_sw + NE);              // BNODES*FH
  float* hB    = hA + (size_t)BNODES*FH;             // BNODES*FH
  float* dinvW = hB + (size_t)BNODES*FH;             // BNODES
  float* dinvU = dinvW + BNODES;                     // BNODES
  float* q     = dinvU + BNODES;                     // BNODES
  float* qpart = q + BNODES;                         // 2*BNODES
  float* score = qpart + 2*BNODES;                   // BNODES
  float* tm    = score + BNODES;                     // BNODES
  float* pmax  = tm + BNODES;                        // 3*NB*4*FH
  float* psum  = pmax + 3*NB*4*FH;                   // 3*NB*4*FH
  int* aliveA  = (int*)(psum + 3*NB*4*FH);           // BNODES
  int* aliveB  = aliveA + BNODES;                    // BNODES
  int* rowptr  = aliveB + BNODES;                    // BNODES+1

  const int TB = 256;
  const int gG  = BNODES / 16;         // 8192 (16 nodes/block)
  const int gNH = BNODES*FH / TB;      // 32768
  const int gL  = BNODES / 64;         // 2048 lin64 blocks
  const int gN  = BNODES / TB;         // 512
  const size_t gathLds = (size_t)NN*32*sizeof(float);   // 128 KB

  k_csr<<<NB, 1024, EPG*sizeof(int2), stream>>>(ei, ea, rowptr, csr_sw, aliveA,
                                                dinvW, dinvU);

  // ===== Layer 1 =====
  k_lin1<<<gNH, TB, 0, stream>>>(x, W1, hB);
  k_gath<0><<<NB*2, 1024, gathLds, stream>>>(rowptr, csr_sw, dinvW, hB, b1, Wp1, hA, qpart);
  k_qfin<<<gN, TB, 0, stream>>>(dinvU, qpart, q);
  k_score<<<gG, TB, 0, stream>>>(rowptr, csr_sw, dinvU, q, bp1, score);
  k_topk<<<NB*4, TB, 0, stream>>>(score, aliveA, KK1, tm, aliveB);
  k_sread<<<NB*4, TB, 0, stream>>>(hA, tm, aliveB, pmax, psum);

  // ===== Layer 2 =====
  k_degs<1><<<gG, TB, 0, stream>>>(rowptr, csr_sw, aliveB, dinvW, dinvU);
  k_lin64<<<gL, TB, 0, stream>>>(hA, tm, W2, hB);
  k_gath<1><<<NB*2, 1024, gathLds, stream>>>(rowptr, csr_sw, dinvW, hB, b2, Wp2, hA, qpart);
  k_qfin<<<gN, TB, 0, stream>>>(dinvU, qpart, q);
  k_score<<<gG, TB, 0, stream>>>(rowptr, csr_sw, dinvU, q, bp2, score);
  k_topk<<<NB*4, TB, 0, stream>>>(score, aliveB, KK2, tm, aliveA);
  k_sread<<<NB*4, TB, 0, stream>>>(hA, tm, aliveA, pmax + NB*4*FH, psum + NB*4*FH);

  // ===== Layer 3 =====
  k_degs<2><<<gG, TB, 0, stream>>>(rowptr, csr_sw, aliveA, dinvW, dinvU);
  k_lin64<<<gL, TB, 0, stream>>>(hA, tm, W3, hB);
  k_gath<2><<<NB*2, 1024, gathLds, stream>>>(rowptr, csr_sw, dinvW, hB, b3, Wp3, hA, qpart);
  k_qfin<<<gN, TB, 0, stream>>>(dinvU, qpart, q);
  k_score<<<gG, TB, 0, stream>>>(rowptr, csr_sw, dinvU, q, bp3, score);
  k_topk<<<NB*4, TB, 0, stream>>>(score, aliveA, KK3, tm, aliveB);
  k_sread<<<NB*4, TB, 0, stream>>>(hA, tm, aliveB, pmax + 2*NB*4*FH, psum + 2*NB*4*FH);

  k_mlp<<<NB, FH, 0, stream>>>(pmax, psum, Wl1, bl1, Wl2, bl2, Wl3, bl3, out);
}

// Round 17
// 445.003 us; speedup vs baseline: 1.0156x; 1.0156x over previous
//
#include <hip/hip_runtime.h>
#include <math.h>

#define NB 128            // graphs
#define NN 1024           // nodes per graph
#define BNODES (NB*NN)    // 131072
#define NE 2097152        // edges
#define EPG (NE/NB)       // 16384 edges per graph (edge list is graph-blocked)
#define EPT (EPG/NN)      // 16 edges per thread in k_csr
#define FH 64             // hidden
#define KK1 820
#define KK2 656
#define KK3 525

// ---------------- one-kernel CSR build + layer-1 degrees ----------------
__global__ __launch_bounds__(1024) void k_csr(const int* __restrict__ ei,
                                              const float* __restrict__ ea,
                                              int* __restrict__ rowptr,
                                              int2* __restrict__ csr_sw,
                                              float* __restrict__ dinvW,
                                              float* __restrict__ dinvU) {
  extern __shared__ int2 lcsr[];          // EPG entries = 128 KB
  __shared__ int cnt[NN];
  __shared__ int cur[NN];
  __shared__ float wsum[NN];
  int b = blockIdx.x, t = threadIdx.x;
  int node = b*NN + t;
  cnt[t] = 0;
  wsum[t] = 0.f;
  __syncthreads();
  int ebase = b*EPG;
  int se[EPT]; int de[EPT]; float we[EPT];
  #pragma unroll
  for (int i = 0; i < EPT; ++i) {
    int e = ebase + i*NN + t;
    se[i] = ei[e];
    de[i] = ei[NE + e] - b*NN;
    we[i] = ea[e];
    atomicAdd(&cnt[de[i]], 1);
    atomicAdd(&wsum[de[i]], we[i]);
  }
  __syncthreads();
  int v = cnt[t];
  for (int off = 1; off < NN; off <<= 1) {
    int u = (t >= off) ? cnt[t - off] : 0;
    __syncthreads();
    cnt[t] += u;
    __syncthreads();
  }
  int excl = cnt[t] - v;
  rowptr[node] = ebase + excl;
  cur[t] = excl;
  dinvW[node] = rsqrtf(1.f + wsum[t]);    // layer-1 weighted degree (all alive)
  dinvU[node] = rsqrtf(1.f + (float)v);   // layer-1 unweighted degree
  if (b == NB-1 && t == NN-1) rowptr[BNODES] = NE;
  __syncthreads();
  #pragma unroll
  for (int i = 0; i < EPT; ++i) {
    int pos = atomicAdd(&cur[de[i]], 1);
    lcsr[pos] = make_int2(se[i], __float_as_int(we[i]));
  }
  __syncthreads();
  float4* dst4 = (float4*)(csr_sw + ebase);
  const float4* src4 = (const float4*)lcsr;
  #pragma unroll
  for (int i = 0; i < EPG/2/NN; ++i)
    dst4[i*NN + t] = src4[i*NN + t];
}

// ---------------- LDS-staged GCN gather: 1 block per (graph, feature-half) ----------------
// L1S=true: stage = x@W1 computed on the fly (layer 1; hB never materialized).
// Batched v[8] LDS loads; __launch_bounds__(1024,4) -> 128-VGPR cap for MLP.
template<int MODE, bool L1S>
__global__ __launch_bounds__(1024, 4) void k_gath(
    const int* __restrict__ rowptr, const int2* __restrict__ csr_sw,
    const float* __restrict__ dinvW, const float* __restrict__ src,  // hB or x
    const float* __restrict__ Wl,                                    // W1 (L1S only)
    const float* __restrict__ bias, const float* __restrict__ Wp,
    float* __restrict__ hA, float* __restrict__ qpart) {
  extern __shared__ float sHB[];        // [NN][32] = 128 KB
  __shared__ float sDW[NN];
  __shared__ float sWp[32];
  __shared__ float sB[32];
  __shared__ float sW1[64];
  int b = blockIdx.x >> 1, half = blockIdx.x & 1;
  int t = threadIdx.x, l8 = t & 7;
  int gbase = b*NN;
  sDW[t] = dinvW[gbase + t];
  if (t < 32) { sWp[t] = Wp[half*32 + t]; sB[t] = bias[half*32 + t]; }
  float4* sHB4 = (float4*)sHB;
  if (L1S) {
    if (t < 32) { sW1[t] = Wl[half*32 + t]; sW1[32 + t] = Wl[64 + half*32 + t]; }
    __syncthreads();
    #pragma unroll
    for (int i = 0; i < 32; ++i) {
      int el = i*1024 + t;
      int n = el >> 5, ff = el & 31;
      float x0 = src[(size_t)(gbase + n)*2];
      float x1 = src[(size_t)(gbase + n)*2 + 1];
      sHB[n*32 + ff] = x0*sW1[ff] + x1*sW1[32 + ff];
    }
  } else {
    const float4* hB4 = (const float4*)src;
    #pragma unroll
    for (int i = 0; i < 8; ++i) {
      int idx = i*1024 + t;
      int n = idx >> 3, j = idx & 7;
      sHB4[n*8 + j] = hB4[(size_t)(gbase + n)*16 + half*8 + j];
    }
  }
  __syncthreads();
  float4 bv = ((const float4*)sB)[l8];
  float4 wp = ((const float4*)sWp)[l8];
  #pragma unroll 1
  for (int pass = 0; pass < 8; ++pass) {
    int n = pass*128 + (t >> 3);
    int gn = gbase + n;
    float dd = sDW[n];
    float4 hv = sHB4[n*8 + l8];
    float dd2 = dd*dd;
    float4 acc;
    acc.x = fmaf(dd2, hv.x, bv.x);
    acc.y = fmaf(dd2, hv.y, bv.y);
    acc.z = fmaf(dd2, hv.z, bv.z);
    acc.w = fmaf(dd2, hv.w, bv.w);
    int r0 = rowptr[gn], r1 = rowptr[gn+1];
    for (int base = r0; base < r1; base += 8) {
      int sj = 0; float cj = 0.f;
      if (base + l8 < r1) {
        int2 p = csr_sw[base + l8];
        sj = p.x - gbase;
        float w = (MODE == 2) ? 1.f : __int_as_float(p.y);
        cj = sDW[sj] * w * dd;          // 0 if src or dst dead
      }
      float4 v[8];
      #pragma unroll
      for (int j = 0; j < 8; ++j) {
        int s = __shfl(sj, j, 8);
        v[j] = sHB4[s*8 + l8];
      }
      #pragma unroll
      for (int j = 0; j < 8; ++j) {
        float c = __shfl(cj, j, 8);
        acc.x = fmaf(c, v[j].x, acc.x);
        acc.y = fmaf(c, v[j].y, acc.y);
        acc.z = fmaf(c, v[j].z, acc.z);
        acc.w = fmaf(c, v[j].w, acc.w);
      }
    }
    acc.x = fmaxf(acc.x, 0.f); acc.y = fmaxf(acc.y, 0.f);
    acc.z = fmaxf(acc.z, 0.f); acc.w = fmaxf(acc.w, 0.f);
    ((float4*)hA)[(size_t)gn*16 + half*8 + l8] = acc;
    float dot = acc.x*wp.x + acc.y*wp.y + acc.z*wp.z + acc.w*wp.w;
    dot += __shfl_xor(dot, 4, 8);
    dot += __shfl_xor(dot, 2, 8);
    dot += __shfl_xor(dot, 1, 8);
    if (l8 == 0) qpart[half*BNODES + gn] = dot;
  }
}

// ---------------- fused pool: qfin + score + topk + tm/alive + next degs ----------------
// One 1024-thread block per graph. NEXTMODE: 1 = ea*mask, 2 = mask, 0 = none.
template<int NEXTMODE>
__global__ __launch_bounds__(1024) void k_pool(
    const int* __restrict__ rowptr, const int2* __restrict__ csr_sw,
    const float* __restrict__ qpart, const float* __restrict__ bp, int k,
    float* __restrict__ tm, int* __restrict__ aliveN,
    float* dinvW, float* dinvU) {       // read current, write next (same bufs)
  __shared__ float sq[NN];
  __shared__ float sdU[NN];
  __shared__ float sc[NN];
  __shared__ float sraw[NN];
  __shared__ int ssel[NN];
  int b = blockIdx.x, t = threadIdx.x;
  int gbase = b*NN;
  float du = dinvU[gbase + t];
  sdU[t] = du;
  sq[t] = du * (qpart[gbase + t] + qpart[BNODES + gbase + t]);
  __syncthreads();
  int l16 = t & 15, g = t >> 4;
  float bpv = bp[0];
  // score: 16-lane group per node, q from LDS
  for (int i = 0; i < 16; ++i) {
    int n = g*16 + i;
    int gn = gbase + n;
    int r0 = rowptr[gn], r1 = rowptr[gn+1];
    float sum = 0.f;
    for (int base = r0; base < r1; base += 16)
      if (base + l16 < r1) sum += sq[csr_sw[base + l16].x - gbase];
    #pragma unroll
    for (int off = 8; off; off >>= 1) sum += __shfl_xor(sum, off, 16);
    if (l16 == 0) {
      float dun = sdU[n];
      float raw = bpv + dun*(sq[n] + sum);
      sraw[n] = raw;
      sc[n] = (dun != 0.f) ? raw : -INFINITY;   // du==0 <=> dead
    }
  }
  __syncthreads();
  // exact jax.lax.top_k rank (ties -> lower index)
  float me = sc[t];
  int rank = 0;
  const float4* sc4 = (const float4*)sc;
  for (int j4 = 0; j4 < NN/4; ++j4) {
    float4 o = sc4[j4];
    int jb = j4*4;
    rank += (o.x > me) || (o.x == me && jb+0 < t);
    rank += (o.y > me) || (o.y == me && jb+1 < t);
    rank += (o.z > me) || (o.z == me && jb+2 < t);
    rank += (o.w > me) || (o.w == me && jb+3 < t);
  }
  int sel = (rank < k) ? 1 : 0;
  ssel[t] = sel;
  aliveN[gbase + t] = sel;
  tm[gbase + t] = sel ? tanhf(sraw[t]) : 0.f;
  __syncthreads();
  if (NEXTMODE != 0) {
    // next-layer degrees with alive mask in LDS
    for (int i = 0; i < 16; ++i) {
      int n = g*16 + i;
      int gn = gbase + n;
      int r0 = rowptr[gn], r1 = rowptr[gn+1];
      float sW = 0.f, sU = 0.f;
      for (int base = r0; base < r1; base += 16)
        if (base + l16 < r1) {
          int2 p = csr_sw[base + l16];
          if (ssel[p.x - gbase]) {
            sW += (NEXTMODE == 2) ? 1.f : __int_as_float(p.y);
            sU += 1.f;
          }
        }
      #pragma unroll
      for (int off = 8; off; off >>= 1) {
        sW += __shfl_xor(sW, off, 16);
        sU += __shfl_xor(sU, off, 16);
      }
      if (l16 == 0) {
        bool dA = ssel[n] != 0;
        dinvW[gn] = dA ? rsqrtf(1.f + sW) : 0.f;
        dinvU[gn] = dA ? rsqrtf(1.f + sU) : 0.f;
      }
    }
  }
}

// ---------------- fused readout partials (+ optional pool-scale @ W) ----------------
// 64-node tile; partials [NB*16][FH]; DOLIN also writes hB = (tm*hA) @ W.
template<bool DOLIN>
__global__ void k_srl(const float* __restrict__ hA, const float* __restrict__ tm,
                      const int* __restrict__ aliveN, const float* __restrict__ W,
                      float* __restrict__ hB,
                      float* __restrict__ pmax, float* __restrict__ psum) {
  __shared__ float sX[64][65];
  __shared__ float sW[64*64];
  __shared__ int sAl[64];
  __shared__ float rm[4][FH], rs[4][FH];
  int t = threadIdx.x;
  int blk = blockIdx.x;
  int nb = blk*64;
  if (DOLIN)
    for (int i = t; i < 1024; i += 256) ((float4*)sW)[i] = ((const float4*)W)[i];
  if (t < 64) sAl[t] = aliveN[nb + t];
  #pragma unroll
  for (int i = 0; i < 16; ++i) {
    int gidx = (nb << 6) + i*256 + t;
    int node = gidx >> 6, f = gidx & 63;
    sX[node - nb][f] = hA[gidx] * tm[node];
  }
  __syncthreads();
  {
    int f = t & 63, r = t >> 6;
    float mx = -INFINITY, sm = 0.f;
    #pragma unroll
    for (int i = 0; i < 16; ++i) {
      int n = r + i*4;
      float v = sX[n][f];
      if (sAl[n]) { mx = fmaxf(mx, v); sm += v; }
    }
    rm[r][f] = mx; rs[r][f] = sm;
  }
  __syncthreads();
  if (t < FH) {
    float m2 = fmaxf(fmaxf(rm[0][t], rm[1][t]), fmaxf(rm[2][t], rm[3][t]));
    float s2 = rs[0][t] + rs[1][t] + rs[2][t] + rs[3][t];
    pmax[blk*FH + t] = m2;
    psum[blk*FH + t] = s2;
  }
  if (DOLIN) {
    int node = t >> 2;
    int f0 = (t & 3) * 16;
    float4 a0 = {0,0,0,0}, a1 = a0, a2 = a0, a3 = a0;
    #pragma unroll 4
    for (int k = 0; k < 64; ++k) {
      float xv = sX[node][k];
      const float4 w0 = *(const float4*)&sW[k*64 + f0];
      const float4 w1 = *(const float4*)&sW[k*64 + f0 + 4];
      const float4 w2 = *(const float4*)&sW[k*64 + f0 + 8];
      const float4 w3 = *(const float4*)&sW[k*64 + f0 + 12];
      a0.x = fmaf(xv, w0.x, a0.x); a0.y = fmaf(xv, w0.y, a0.y);
      a0.z = fmaf(xv, w0.z, a0.z); a0.w = fmaf(xv, w0.w, a0.w);
      a1.x = fmaf(xv, w1.x, a1.x); a1.y = fmaf(xv, w1.y, a1.y);
      a1.z = fmaf(xv, w1.z, a1.z); a1.w = fmaf(xv, w1.w, a1.w);
      a2.x = fmaf(xv, w2.x, a2.x); a2.y = fmaf(xv, w2.y, a2.y);
      a2.z = fmaf(xv, w2.z, a2.z); a2.w = fmaf(xv, w2.w, a2.w);
      a3.x = fmaf(xv, w3.x, a3.x); a3.y = fmaf(xv, w3.y, a3.y);
      a3.z = fmaf(xv, w3.z, a3.z); a3.w = fmaf(xv, w3.w, a3.w);
    }
    float4* dst = (float4*)(hB + (size_t)(nb + node)*FH + f0);
    dst[0] = a0; dst[1] = a1; dst[2] = a2; dst[3] = a3;
  }
}

// ---------------- partial reduce + MLP head + log_softmax ----------------
__global__ void k_mlp(const float* __restrict__ pmax, const float* __restrict__ psum,
                      const float* __restrict__ Wl1, const float* __restrict__ bl1,
                      const float* __restrict__ Wl2, const float* __restrict__ bl2,
                      const float* __restrict__ Wl3, const float* __restrict__ bl3,
                      float* __restrict__ out) {
  __shared__ float sg[2*FH];
  __shared__ float l1[FH];
  __shared__ float l2[FH/2];
  __shared__ float l3[2];
  int b = blockIdx.x, t = threadIdx.x;
  const float kf[3] = {(float)KK1, (float)KK2, (float)KK3};
  float gm = 0.f, gs = 0.f;
  #pragma unroll
  for (int l = 0; l < 3; ++l) {
    const float* pm = pmax + (size_t)l*NB*16*FH + (b*16)*FH;
    const float* ps = psum + (size_t)l*NB*16*FH + (b*16)*FH;
    float mm = -INFINITY, ss = 0.f;
    #pragma unroll
    for (int p = 0; p < 16; ++p) {
      mm = fmaxf(mm, pm[p*FH + t]);
      ss += ps[p*FH + t];
    }
    gm += mm;
    gs += ss / kf[l];
  }
  sg[t] = gm;
  sg[FH + t] = gs;
  __syncthreads();
  float acc = bl1[t];
  #pragma unroll
  for (int k = 0; k < 2*FH; ++k) acc = fmaf(sg[k], Wl1[k*FH + t], acc);
  l1[t] = fmaxf(acc, 0.f);
  __syncthreads();
  if (t < 32) {
    float a2 = bl2[t];
    #pragma unroll
    for (int k = 0; k < FH; ++k) a2 = fmaf(l1[k], Wl2[k*32 + t], a2);
    l2[t] = fmaxf(a2, 0.f);
  }
  __syncthreads();
  if (t < 2) {
    float a3 = bl3[t];
    #pragma unroll
    for (int k = 0; k < 32; ++k) a3 = fmaf(l2[k], Wl3[k*2 + t], a3);
    l3[t] = a3;
  }
  __syncthreads();
  if (t == 0) {
    float m = fmaxf(l3[0], l3[1]);
    float lse = m + logf(expf(l3[0]-m) + expf(l3[1]-m));
    out[b*2+0] = l3[0] - lse;
    out[b*2+1] = l3[1] - lse;
  }
}

extern "C" void kernel_launch(void* const* d_in, const int* in_sizes, int n_in,
                              void* d_out, int out_size, void* d_ws, size_t ws_size,
                              hipStream_t stream) {
  const float* x   = (const float*)d_in[0];
  const float* ea  = (const float*)d_in[1];
  const float* W1  = (const float*)d_in[2];
  const float* b1  = (const float*)d_in[3];
  const float* Wp1 = (const float*)d_in[4];
  const float* bp1 = (const float*)d_in[5];
  const float* W2  = (const float*)d_in[6];
  const float* b2  = (const float*)d_in[7];
  const float* Wp2 = (const float*)d_in[8];
  const float* bp2 = (const float*)d_in[9];
  const float* W3  = (const float*)d_in[10];
  const float* b3  = (const float*)d_in[11];
  const float* Wp3 = (const float*)d_in[12];
  const float* bp3 = (const float*)d_in[13];
  const float* Wl1 = (const float*)d_in[14];
  const float* bl1 = (const float*)d_in[15];
  const float* Wl2 = (const float*)d_in[16];
  const float* bl2 = (const float*)d_in[17];
  const float* Wl3 = (const float*)d_in[18];
  const float* bl3 = (const float*)d_in[19];
  const int*   ei  = (const int*)d_in[20];
  float* out = (float*)d_out;

  int2* csr_sw = (int2*)d_ws;                        // NE
  float* hA    = (float*)(csr_sw + NE);              // BNODES*FH
  float* hB    = hA + (size_t)BNODES*FH;             // BNODES*FH
  float* dinvW = hB + (size_t)BNODES*FH;             // BNODES
  float* dinvU = dinvW + BNODES;                     // BNODES
  float* qpart = dinvU + BNODES;                     // 2*BNODES
  float* tm    = qpart + 2*BNODES;                   // BNODES
  float* pmax  = tm + BNODES;                        // 3*NB*16*FH
  float* psum  = pmax + 3*NB*16*FH;                  // 3*NB*16*FH
  int* aliveN  = (int*)(psum + 3*NB*16*FH);          // BNODES
  int* rowptr  = aliveN + BNODES;                    // BNODES+1

  const size_t gathLds = (size_t)NN*32*sizeof(float);   // 128 KB
  const int gS = BNODES/64;                             // 2048 srl blocks

  k_csr<<<NB, 1024, EPG*sizeof(int2), stream>>>(ei, ea, rowptr, csr_sw, dinvW, dinvU);

  // ===== Layer 1 =====
  k_gath<0,true><<<NB*2, 1024, gathLds, stream>>>(rowptr, csr_sw, dinvW, x, W1, b1, Wp1, hA, qpart);
  k_pool<1><<<NB, 1024, 0, stream>>>(rowptr, csr_sw, qpart, bp1, KK1, tm, aliveN, dinvW, dinvU);
  k_srl<true><<<gS, 256, 0, stream>>>(hA, tm, aliveN, W2, hB, pmax, psum);

  // ===== Layer 2 =====
  k_gath<1,false><<<NB*2, 1024, gathLds, stream>>>(rowptr, csr_sw, dinvW, hB, W1, b2, Wp2, hA, qpart);
  k_pool<2><<<NB, 1024, 0, stream>>>(rowptr, csr_sw, qpart, bp2, KK2, tm, aliveN, dinvW, dinvU);
  k_srl<true><<<gS, 256, 0, stream>>>(hA, tm, aliveN, W3, hB, pmax + NB*16*FH, psum + NB*16*FH);

  // ===== Layer 3 =====
  k_gath<2,false><<<NB*2, 1024, gathLds, stream>>>(rowptr, csr_sw, dinvW, hB, W1, b3, Wp3, hA, qpart);
  k_pool<0><<<NB, 1024, 0, stream>>>(rowptr, csr_sw, qpart, bp3, KK3, tm, aliveN, dinvW, dinvU);
  k_srl<false><<<gS, 256, 0, stream>>>(hA, tm, aliveN, W3, hB, pmax + 2*NB*16*FH, psum + 2*NB*16*FH);

  k_mlp<<<NB, FH, 0, stream>>>(pmax, psum, Wl1, bl1, Wl2, bl2, Wl3, bl3, out);
}

// Round 18
// 375.063 us; speedup vs baseline: 1.2050x; 1.1865x over previous
//
#include <hip/hip_runtime.h>
#include <math.h>

#define NB 128            // graphs
#define NN 1024           // nodes per graph
#define BNODES (NB*NN)    // 131072
#define NE 2097152        // edges
#define EPG (NE/NB)       // 16384 edges per graph (edge list is graph-blocked)
#define EPT (EPG/NN)      // 16 edges per thread in k_csr
#define FH 64             // hidden
#define KK1 820
#define KK2 656
#define KK3 525

// ---------------- one-kernel CSR build + layer-1 degrees ----------------
__global__ __launch_bounds__(1024) void k_csr(const int* __restrict__ ei,
                                              const float* __restrict__ ea,
                                              int* __restrict__ rowptr,
                                              int2* __restrict__ csr_sw,
                                              float* __restrict__ dinvW,
                                              float* __restrict__ dinvU) {
  extern __shared__ int2 lcsr[];          // EPG entries = 128 KB
  __shared__ int cnt[NN];
  __shared__ int cur[NN];
  __shared__ float wsum[NN];
  int b = blockIdx.x, t = threadIdx.x;
  int node = b*NN + t;
  cnt[t] = 0;
  wsum[t] = 0.f;
  __syncthreads();
  int ebase = b*EPG;
  int se[EPT]; int de[EPT]; float we[EPT];
  #pragma unroll
  for (int i = 0; i < EPT; ++i) {
    int e = ebase + i*NN + t;
    se[i] = ei[e];
    de[i] = ei[NE + e] - b*NN;
    we[i] = ea[e];
    atomicAdd(&cnt[de[i]], 1);
    atomicAdd(&wsum[de[i]], we[i]);
  }
  __syncthreads();
  int v = cnt[t];
  for (int off = 1; off < NN; off <<= 1) {
    int u = (t >= off) ? cnt[t - off] : 0;
    __syncthreads();
    cnt[t] += u;
    __syncthreads();
  }
  int excl = cnt[t] - v;
  rowptr[node] = ebase + excl;
  cur[t] = excl;
  dinvW[node] = rsqrtf(1.f + wsum[t]);    // layer-1 weighted degree (all alive)
  dinvU[node] = rsqrtf(1.f + (float)v);   // layer-1 unweighted degree
  if (b == NB-1 && t == NN-1) rowptr[BNODES] = NE;
  __syncthreads();
  #pragma unroll
  for (int i = 0; i < EPT; ++i) {
    int pos = atomicAdd(&cur[de[i]], 1);
    lcsr[pos] = make_int2(se[i], __float_as_int(we[i]));
  }
  __syncthreads();
  float4* dst4 = (float4*)(csr_sw + ebase);
  const float4* src4 = (const float4*)lcsr;
  #pragma unroll
  for (int i = 0; i < EPG/2/NN; ++i)
    dst4[i*NN + t] = src4[i*NN + t];
}

// ---------------- LDS-staged GCN gather: 1 block per (graph, feature-half) ----------------
// L1S=true: stage = x@W1 computed on the fly (layer 1; hB never materialized).
template<int MODE, bool L1S>
__global__ __launch_bounds__(1024, 4) void k_gath(
    const int* __restrict__ rowptr, const int2* __restrict__ csr_sw,
    const float* __restrict__ dinvW, const float* __restrict__ src,  // hB or x
    const float* __restrict__ Wl,                                    // W1 (L1S only)
    const float* __restrict__ bias, const float* __restrict__ Wp,
    float* __restrict__ hA, float* __restrict__ qpart) {
  extern __shared__ float sHB[];        // [NN][32] = 128 KB
  __shared__ float sDW[NN];
  __shared__ float sWp[32];
  __shared__ float sB[32];
  __shared__ float sW1[64];
  int b = blockIdx.x >> 1, half = blockIdx.x & 1;
  int t = threadIdx.x, l8 = t & 7;
  int gbase = b*NN;
  sDW[t] = dinvW[gbase + t];
  if (t < 32) { sWp[t] = Wp[half*32 + t]; sB[t] = bias[half*32 + t]; }
  float4* sHB4 = (float4*)sHB;
  if (L1S) {
    if (t < 32) { sW1[t] = Wl[half*32 + t]; sW1[32 + t] = Wl[64 + half*32 + t]; }
    __syncthreads();
    #pragma unroll
    for (int i = 0; i < 32; ++i) {
      int el = i*1024 + t;
      int n = el >> 5, ff = el & 31;
      float x0 = src[(size_t)(gbase + n)*2];
      float x1 = src[(size_t)(gbase + n)*2 + 1];
      sHB[n*32 + ff] = x0*sW1[ff] + x1*sW1[32 + ff];
    }
  } else {
    const float4* hB4 = (const float4*)src;
    #pragma unroll
    for (int i = 0; i < 8; ++i) {
      int idx = i*1024 + t;
      int n = idx >> 3, j = idx & 7;
      sHB4[n*8 + j] = hB4[(size_t)(gbase + n)*16 + half*8 + j];
    }
  }
  __syncthreads();
  float4 bv = ((const float4*)sB)[l8];
  float4 wp = ((const float4*)sWp)[l8];
  #pragma unroll 1
  for (int pass = 0; pass < 8; ++pass) {
    int n = pass*128 + (t >> 3);
    int gn = gbase + n;
    float dd = sDW[n];
    float4 hv = sHB4[n*8 + l8];
    float dd2 = dd*dd;
    float4 acc;
    acc.x = fmaf(dd2, hv.x, bv.x);
    acc.y = fmaf(dd2, hv.y, bv.y);
    acc.z = fmaf(dd2, hv.z, bv.z);
    acc.w = fmaf(dd2, hv.w, bv.w);
    int r0 = rowptr[gn], r1 = rowptr[gn+1];
    for (int base = r0; base < r1; base += 8) {
      int sj = 0; float cj = 0.f;
      if (base + l8 < r1) {
        int2 p = csr_sw[base + l8];
        sj = p.x - gbase;
        float w = (MODE == 2) ? 1.f : __int_as_float(p.y);
        cj = sDW[sj] * w * dd;          // 0 if src or dst dead
      }
      float4 v[8];
      #pragma unroll
      for (int j = 0; j < 8; ++j) {
        int s = __shfl(sj, j, 8);
        v[j] = sHB4[s*8 + l8];
      }
      #pragma unroll
      for (int j = 0; j < 8; ++j) {
        float c = __shfl(cj, j, 8);
        acc.x = fmaf(c, v[j].x, acc.x);
        acc.y = fmaf(c, v[j].y, acc.y);
        acc.z = fmaf(c, v[j].z, acc.z);
        acc.w = fmaf(c, v[j].w, acc.w);
      }
    }
    acc.x = fmaxf(acc.x, 0.f); acc.y = fmaxf(acc.y, 0.f);
    acc.z = fmaxf(acc.z, 0.f); acc.w = fmaxf(acc.w, 0.f);
    ((float4*)hA)[(size_t)gn*16 + half*8 + l8] = acc;
    float dot = acc.x*wp.x + acc.y*wp.y + acc.z*wp.z + acc.w*wp.w;
    dot += __shfl_xor(dot, 4, 8);
    dot += __shfl_xor(dot, 2, 8);
    dot += __shfl_xor(dot, 1, 8);
    if (l8 == 0) qpart[half*BNODES + gn] = dot;
  }
}

// ---------------- q finalize: q = dinvU * (qp0 + qp1) ----------------
__global__ void k_qfin(const float* __restrict__ dinvU, const float* __restrict__ qp,
                       float* __restrict__ q) {
  int i = blockIdx.x*256 + threadIdx.x;
  if (i < BNODES) q[i] = dinvU[i]*(qp[i] + qp[BNODES + i]);
}

// ---------------- scoring aggregation (q self-masking, full grid) ----------------
__global__ void k_score(const int* __restrict__ rowptr, const int2* __restrict__ csr_sw,
                        const float* __restrict__ dinvU, const float* __restrict__ q,
                        const float* __restrict__ bp, float* __restrict__ score) {
  int t = threadIdx.x;
  int l16 = t & 15;
  int d = blockIdx.x*16 + (t >> 4);
  float du = dinvU[d];
  float sum = 0.f;
  if (du != 0.f) {
    int r0 = rowptr[d], r1 = rowptr[d+1];
    for (int base = r0; base < r1; base += 16)
      if (base + l16 < r1) sum += q[csr_sw[base + l16].x];
  }
  #pragma unroll
  for (int off = 8; off; off >>= 1) sum += __shfl_xor(sum, off, 16);
  if (l16 == 0) score[d] = bp[0] + du*(q[d] + sum);
}

// ---------------- top-k rank: 4 blocks/graph; alive test = dinvU != 0 ----------------
__global__ void k_topk(const float* __restrict__ score,
                       const float* __restrict__ dinvU, int k,
                       float* __restrict__ tm, int* __restrict__ aliveN) {
  __shared__ float sc[NN];
  int b = blockIdx.x >> 2, p = blockIdx.x & 3;
  int t = threadIdx.x;
  int gbase = b*NN;
  #pragma unroll
  for (int i = 0; i < 4; ++i) {
    int n = i*256 + t;
    sc[n] = (dinvU[gbase + n] != 0.f) ? score[gbase + n] : -INFINITY;
  }
  __syncthreads();
  int n = p*256 + t;              // this thread's node
  int node = gbase + n;
  float me = sc[n];
  float raw = score[node];
  int rank = 0;
  const float4* sc4 = (const float4*)sc;
  for (int j4 = 0; j4 < NN/4; ++j4) {
    float4 o = sc4[j4];
    int jb = j4*4;
    rank += (o.x > me) || (o.x == me && jb+0 < n);
    rank += (o.y > me) || (o.y == me && jb+1 < n);
    rank += (o.z > me) || (o.z == me && jb+2 < n);
    rank += (o.w > me) || (o.w == me && jb+3 < n);
  }
  int sel = (rank < k) ? 1 : 0;
  aliveN[node] = sel;
  tm[node] = sel ? tanhf(raw) : 0.f;
}

// ---------------- degrees (next layer): 16-lane group per node, full grid ----------------
template<int MODE>
__global__ void k_degs(const int* __restrict__ rowptr, const int2* __restrict__ csr_sw,
                       const int* __restrict__ alive,
                       float* __restrict__ dinvW, float* __restrict__ dinvU) {
  int t = threadIdx.x;
  int l16 = t & 15;
  int d = blockIdx.x*16 + (t >> 4);
  int r0 = rowptr[d], r1 = rowptr[d+1];
  float sW = 0.f, sU = 0.f;
  for (int base = r0; base < r1; base += 16) {
    if (base + l16 < r1) {
      int2 p = csr_sw[base + l16];
      if (alive[p.x]) { sW += (MODE == 2) ? 1.f : __int_as_float(p.y); sU += 1.f; }
    }
  }
  #pragma unroll
  for (int off = 8; off; off >>= 1) {
    sW += __shfl_xor(sW, off, 16);
    sU += __shfl_xor(sU, off, 16);
  }
  if (l16 == 0) {
    bool dA = (alive[d] != 0);
    dinvW[d] = dA ? rsqrtf(1.f + sW) : 0.f;
    dinvU[d] = dA ? rsqrtf(1.f + sU) : 0.f;
  }
}

// ---------------- fused readout partials (+ optional pool-scale @ W) ----------------
// 64-node tile; partials [NB*16][FH]; DOLIN also writes hB = (tm*hA) @ W.
template<bool DOLIN>
__global__ void k_srl(const float* __restrict__ hA, const float* __restrict__ tm,
                      const int* __restrict__ aliveN, const float* __restrict__ W,
                      float* __restrict__ hB,
                      float* __restrict__ pmax, float* __restrict__ psum) {
  __shared__ float sX[64][65];
  __shared__ float sW[64*64];
  __shared__ int sAl[64];
  __shared__ float rm[4][FH], rs[4][FH];
  int t = threadIdx.x;
  int blk = blockIdx.x;
  int nb = blk*64;
  if (DOLIN)
    for (int i = t; i < 1024; i += 256) ((float4*)sW)[i] = ((const float4*)W)[i];
  if (t < 64) sAl[t] = aliveN[nb + t];
  #pragma unroll
  for (int i = 0; i < 16; ++i) {
    int gidx = (nb << 6) + i*256 + t;
    int node = gidx >> 6, f = gidx & 63;
    sX[node - nb][f] = hA[gidx] * tm[node];
  }
  __syncthreads();
  {
    int f = t & 63, r = t >> 6;
    float mx = -INFINITY, sm = 0.f;
    #pragma unroll
    for (int i = 0; i < 16; ++i) {
      int n = r + i*4;
      float v = sX[n][f];
      if (sAl[n]) { mx = fmaxf(mx, v); sm += v; }
    }
    rm[r][f] = mx; rs[r][f] = sm;
  }
  __syncthreads();
  if (t < FH) {
    float m2 = fmaxf(fmaxf(rm[0][t], rm[1][t]), fmaxf(rm[2][t], rm[3][t]));
    float s2 = rs[0][t] + rs[1][t] + rs[2][t] + rs[3][t];
    pmax[blk*FH + t] = m2;
    psum[blk*FH + t] = s2;
  }
  if (DOLIN) {
    int node = t >> 2;
    int f0 = (t & 3) * 16;
    float4 a0 = {0,0,0,0}, a1 = a0, a2 = a0, a3 = a0;
    #pragma unroll 4
    for (int k = 0; k < 64; ++k) {
      float xv = sX[node][k];
      const float4 w0 = *(const float4*)&sW[k*64 + f0];
      const float4 w1 = *(const float4*)&sW[k*64 + f0 + 4];
      const float4 w2 = *(const float4*)&sW[k*64 + f0 + 8];
      const float4 w3 = *(const float4*)&sW[k*64 + f0 + 12];
      a0.x = fmaf(xv, w0.x, a0.x); a0.y = fmaf(xv, w0.y, a0.y);
      a0.z = fmaf(xv, w0.z, a0.z); a0.w = fmaf(xv, w0.w, a0.w);
      a1.x = fmaf(xv, w1.x, a1.x); a1.y = fmaf(xv, w1.y, a1.y);
      a1.z = fmaf(xv, w1.z, a1.z); a1.w = fmaf(xv, w1.w, a1.w);
      a2.x = fmaf(xv, w2.x, a2.x); a2.y = fmaf(xv, w2.y, a2.y);
      a2.z = fmaf(xv, w2.z, a2.z); a2.w = fmaf(xv, w2.w, a2.w);
      a3.x = fmaf(xv, w3.x, a3.x); a3.y = fmaf(xv, w3.y, a3.y);
      a3.z = fmaf(xv, w3.z, a3.z); a3.w = fmaf(xv, w3.w, a3.w);
    }
    float4* dst = (float4*)(hB + (size_t)(nb + node)*FH + f0);
    dst[0] = a0; dst[1] = a1; dst[2] = a2; dst[3] = a3;
  }
}

// ---------------- partial reduce + MLP head + log_softmax ----------------
__global__ void k_mlp(const float* __restrict__ pmax, const float* __restrict__ psum,
                      const float* __restrict__ Wl1, const float* __restrict__ bl1,
                      const float* __restrict__ Wl2, const float* __restrict__ bl2,
                      const float* __restrict__ Wl3, const float* __restrict__ bl3,
                      float* __restrict__ out) {
  __shared__ float sg[2*FH];
  __shared__ float l1[FH];
  __shared__ float l2[FH/2];
  __shared__ float l3[2];
  int b = blockIdx.x, t = threadIdx.x;
  const float kf[3] = {(float)KK1, (float)KK2, (float)KK3};
  float gm = 0.f, gs = 0.f;
  #pragma unroll
  for (int l = 0; l < 3; ++l) {
    const float* pm = pmax + (size_t)l*NB*16*FH + (b*16)*FH;
    const float* ps = psum + (size_t)l*NB*16*FH + (b*16)*FH;
    float mm = -INFINITY, ss = 0.f;
    #pragma unroll
    for (int p = 0; p < 16; ++p) {
      mm = fmaxf(mm, pm[p*FH + t]);
      ss += ps[p*FH + t];
    }
    gm += mm;
    gs += ss / kf[l];
  }
  sg[t] = gm;
  sg[FH + t] = gs;
  __syncthreads();
  float acc = bl1[t];
  #pragma unroll
  for (int k = 0; k < 2*FH; ++k) acc = fmaf(sg[k], Wl1[k*FH + t], acc);
  l1[t] = fmaxf(acc, 0.f);
  __syncthreads();
  if (t < 32) {
    float a2 = bl2[t];
    #pragma unroll
    for (int k = 0; k < FH; ++k) a2 = fmaf(l1[k], Wl2[k*32 + t], a2);
    l2[t] = fmaxf(a2, 0.f);
  }
  __syncthreads();
  if (t < 2) {
    float a3 = bl3[t];
    #pragma unroll
    for (int k = 0; k < 32; ++k) a3 = fmaf(l2[k], Wl3[k*2 + t], a3);
    l3[t] = a3;
  }
  __syncthreads();
  if (t == 0) {
    float m = fmaxf(l3[0], l3[1]);
    float lse = m + logf(expf(l3[0]-m) + expf(l3[1]-m));
    out[b*2+0] = l3[0] - lse;
    out[b*2+1] = l3[1] - lse;
  }
}

extern "C" void kernel_launch(void* const* d_in, const int* in_sizes, int n_in,
                              void* d_out, int out_size, void* d_ws, size_t ws_size,
                              hipStream_t stream) {
  const float* x   = (const float*)d_in[0];
  const float* ea  = (const float*)d_in[1];
  const float* W1  = (const float*)d_in[2];
  const float* b1  = (const float*)d_in[3];
  const float* Wp1 = (const float*)d_in[4];
  const float* bp1 = (const float*)d_in[5];
  const float* W2  = (const float*)d_in[6];
  const float* b2  = (const float*)d_in[7];
  const float* Wp2 = (const float*)d_in[8];
  const float* bp2 = (const float*)d_in[9];
  const float* W3  = (const float*)d_in[10];
  const float* b3  = (const float*)d_in[11];
  const float* Wp3 = (const float*)d_in[12];
  const float* bp3 = (const float*)d_in[13];
  const float* Wl1 = (const float*)d_in[14];
  const float* bl1 = (const float*)d_in[15];
  const float* Wl2 = (const float*)d_in[16];
  const float* bl2 = (const float*)d_in[17];
  const float* Wl3 = (const float*)d_in[18];
  const float* bl3 = (const float*)d_in[19];
  const int*   ei  = (const int*)d_in[20];
  float* out = (float*)d_out;

  int2* csr_sw = (int2*)d_ws;                        // NE
  float* hA    = (float*)(csr_sw + NE);              // BNODES*FH
  float* hB    = hA + (size_t)BNODES*FH;             // BNODES*FH
  float* dinvW = hB + (size_t)BNODES*FH;             // BNODES
  float* dinvU = dinvW + BNODES;                     // BNODES
  float* qpart = dinvU + BNODES;                     // 2*BNODES
  float* q     = qpart + 2*BNODES;                   // BNODES
  float* score = q + BNODES;                         // BNODES
  float* tm    = score + BNODES;                     // BNODES
  float* pmax  = tm + BNODES;                        // 3*NB*16*FH
  float* psum  = pmax + 3*NB*16*FH;                  // 3*NB*16*FH
  int* aliveN  = (int*)(psum + 3*NB*16*FH);          // BNODES
  int* rowptr  = aliveN + BNODES;                    // BNODES+1

  const size_t gathLds = (size_t)NN*32*sizeof(float);   // 128 KB
  const int gS = BNODES/64;                             // 2048 srl blocks
  const int gG = BNODES/16;                             // 8192 score/degs blocks
  const int gN = BNODES/256;                            // 512

  k_csr<<<NB, 1024, EPG*sizeof(int2), stream>>>(ei, ea, rowptr, csr_sw, dinvW, dinvU);

  // ===== Layer 1 =====
  k_gath<0,true><<<NB*2, 1024, gathLds, stream>>>(rowptr, csr_sw, dinvW, x, W1, b1, Wp1, hA, qpart);
  k_qfin<<<gN, 256, 0, stream>>>(dinvU, qpart, q);
  k_score<<<gG, 256, 0, stream>>>(rowptr, csr_sw, dinvU, q, bp1, score);
  k_topk<<<NB*4, 256, 0, stream>>>(score, dinvU, KK1, tm, aliveN);
  k_srl<true><<<gS, 256, 0, stream>>>(hA, tm, aliveN, W2, hB, pmax, psum);
  k_degs<1><<<gG, 256, 0, stream>>>(rowptr, csr_sw, aliveN, dinvW, dinvU);

  // ===== Layer 2 =====
  k_gath<1,false><<<NB*2, 1024, gathLds, stream>>>(rowptr, csr_sw, dinvW, hB, W1, b2, Wp2, hA, qpart);
  k_qfin<<<gN, 256, 0, stream>>>(dinvU, qpart, q);
  k_score<<<gG, 256, 0, stream>>>(rowptr, csr_sw, dinvU, q, bp2, score);
  k_topk<<<NB*4, 256, 0, stream>>>(score, dinvU, KK2, tm, aliveN);
  k_srl<true><<<gS, 256, 0, stream>>>(hA, tm, aliveN, W3, hB, pmax + NB*16*FH, psum + NB*16*FH);
  k_degs<2><<<gG, 256, 0, stream>>>(rowptr, csr_sw, aliveN, dinvW, dinvU);

  // ===== Layer 3 =====
  k_gath<2,false><<<NB*2, 1024, gathLds, stream>>>(rowptr, csr_sw, dinvW, hB, W1, b3, Wp3, hA, qpart);
  k_qfin<<<gN, 256, 0, stream>>>(dinvU, qpart, q);
  k_score<<<gG, 256, 0, stream>>>(rowptr, csr_sw, dinvU, q, bp3, score);
  k_topk<<<NB*4, 256, 0, stream>>>(score, dinvU, KK3, tm, aliveN);
  k_srl<false><<<gS, 256, 0, stream>>>(hA, tm, aliveN, W3, hB, pmax + 2*NB*16*FH, psum + 2*NB*16*FH);

  k_mlp<<<NB, FH, 0, stream>>>(pmax, psum, Wl1, bl1, Wl2, bl2, Wl3, bl3, out);
}